// Round 2
// baseline (2334.771 us; speedup 1.0000x reference)
//
#include <hip/hip_runtime.h>
#include <cstdint>
#include <cstddef>

// Problem constants (fixed by reference)
#define NN 6000
#define WPR 96        // u64 words per bitmask row (94 used + pad)
#define NWORDS 94     // ceil(6000/64)
#define LK_ALPHA 0.2f

// d_out layout (flat f32, reference tuple order)
#define OFF_OUTPUT 0
#define OFF_BETA   48000
#define OFF_EMB1   66000
#define OFF_COM1   450000
#define OFF_COM2   834000
#define OFF_EMB2   1218000
#define OFF_EMB    1602000

typedef unsigned long long u64;

__device__ __forceinline__ float wsum64(float v) {
#pragma unroll
  for (int off = 32; off > 0; off >>= 1) v += __shfl_xor(v, off);
  return v;
}
__device__ __forceinline__ float wmax64(float v) {
#pragma unroll
  for (int off = 32; off > 0; off >>= 1) v = fmaxf(v, __shfl_xor(v, off));
  return v;
}

// ---------------------------------------------------------------------------
// 1. Pack 0/1 int32 adjacency into bitmasks (1 bit per edge).
//    One wave packs one 64-bit word via ballot. Pads words >= NWORDS to 0.
// ---------------------------------------------------------------------------
__global__ __launch_bounds__(256) void pack_kernel(const int* __restrict__ sadj,
                                                   const int* __restrict__ fadj,
                                                   u64* __restrict__ sbits,
                                                   u64* __restrict__ fbits) {
  const int lane = threadIdx.x & 63;
  const int wid = (blockIdx.x * 256 + threadIdx.x) >> 6;
  const int nw = (gridDim.x * 256) >> 6;
  const int per_mat = NN * WPR;
  for (int t = wid; t < 2 * per_mat; t += nw) {
    int m = t / per_mat;                 // compile-time-const divisors -> magic mul
    int rem = t - m * per_mat;
    int row = rem / WPR;
    int wi = rem - row * WPR;
    const int* adj = m ? fadj : sadj;
    int j = wi * 64 + lane;
    int pred = 0;
    if (j < NN) pred = (adj[(size_t)row * NN + j] != 0);
    u64 mask = __ballot(pred);
    if (lane == 0) (m ? fbits : sbits)[row * WPR + wi] = mask;
  }
}

// ---------------------------------------------------------------------------
// 2. Wh = X @ W  (M=6000, N=64, K runtime), fused f = Wh@a[:64], g = Wh@a[64:]
//    Block: 4 waves x 4 rows each = 16 rows. lane = output dim.
// ---------------------------------------------------------------------------
struct GemmArgs { const float* X; const float* W; const float* A; float* wh; float* f; float* g; };
struct GemmArgs4 { GemmArgs a[4]; };

__global__ __launch_bounds__(256) void gemm_fg_kernel(GemmArgs4 P, int K) {
  GemmArgs A = P.a[blockIdx.y];
  const int w = threadIdx.x >> 6, lane = threadIdx.x & 63;
  const int r0 = blockIdx.x * 16 + w * 4;
  float acc[4] = {0.f, 0.f, 0.f, 0.f};
  const float* X0 = A.X + (size_t)r0 * K;
  for (int k = 0; k < K; k += 4) {
    float xa[4][4];
    *(float4*)xa[0] = *(const float4*)(X0 + k);
    *(float4*)xa[1] = *(const float4*)(X0 + K + k);
    *(float4*)xa[2] = *(const float4*)(X0 + 2 * (size_t)K + k);
    *(float4*)xa[3] = *(const float4*)(X0 + 3 * (size_t)K + k);
#pragma unroll
    for (int kk = 0; kk < 4; ++kk) {
      float wv = A.W[(size_t)(k + kk) * 64 + lane];
#pragma unroll
      for (int r = 0; r < 4; ++r) acc[r] = fmaf(xa[r][kk], wv, acc[r]);
    }
  }
  float af = A.A[lane], ag = A.A[64 + lane];
#pragma unroll
  for (int r = 0; r < 4; ++r) {
    A.wh[(size_t)(r0 + r) * 64 + lane] = acc[r];
    float pf = wsum64(acc[r] * af);
    float pg = wsum64(acc[r] * ag);
    if (lane == 0) { A.f[r0 + r] = pf; A.g[r0 + r] = pg; }
  }
}

// ---------------------------------------------------------------------------
// 3. maxg[i] = max over active j of g[j]  (exact softmax max via monotone lr)
//    One wave per 4 rows: amortizes the g stream 4x vs 1 row/wave.
// ---------------------------------------------------------------------------
struct MaxgArgs { const u64* bits; const float* g; float* mg; };
struct MaxgArgs4 { MaxgArgs a[4]; };

__global__ __launch_bounds__(256) void maxg_kernel(MaxgArgs4 P) {
  MaxgArgs A = P.a[blockIdx.y];
  const int w = threadIdx.x >> 6, lane = threadIdx.x & 63;
  const int r0 = blockIdx.x * 16 + w * 4;   // 4 rows per wave
  const u64* br = A.bits + (size_t)r0 * WPR;
  float m[4] = {-INFINITY, -INFINITY, -INFINITY, -INFINITY};
  for (int t = 0; t < NWORDS; ++t) {
    float gv = A.g[t * 64 + lane];          // g padded to 6144 floats
    u64 w0 = br[t];
    u64 w1 = br[WPR + t];
    u64 w2 = br[2 * WPR + t];
    u64 w3 = br[3 * WPR + t];
    if ((w0 >> lane) & 1ull) m[0] = fmaxf(m[0], gv);
    if ((w1 >> lane) & 1ull) m[1] = fmaxf(m[1], gv);
    if ((w2 >> lane) & 1ull) m[2] = fmaxf(m[2], gv);
    if ((w3 >> lane) & 1ull) m[3] = fmaxf(m[3], gv);
  }
#pragma unroll
  for (int r = 0; r < 4; ++r) {
    float mm = wmax64(m[r]);
    if (lane == 0) A.mg[r0 + r] = mm;
  }
}

// ---------------------------------------------------------------------------
// 4. Masked-softmax aggregation:  out[i,:] = softmax_mask(lr(f_i+g_j)) @ Wh
//    MODE 0: elu epilogue (layer-1 h).  MODE 1: elu + row log_softmax (emb out).
//    Block: 32 rows (4 waves x 8), j-tiles of 64 staged in LDS.
// ---------------------------------------------------------------------------
struct AggArgs { const u64* bits; const float* f; const float* g; const float* mg;
                 const float* wh; float* out; };
struct AggArgs4 { AggArgs a[4]; };

template <int MODE>
__global__ __launch_bounds__(256) void agg_kernel(AggArgs4 P) {
  AggArgs A = P.a[blockIdx.y];
  __shared__ float whs[64][64];      // Wh j-tile [j][d], 16 KB
  __shared__ float Ps[4][8][64];     // per-wave P tile [row][j], 8 KB
  const int w = threadIdx.x >> 6, lane = threadIdx.x & 63;
  const int rbase = blockIdx.x * 32 + w * 8;

  float fr[8], mr[8], acc[8], sp[8];
  int boff[8];
#pragma unroll
  for (int k = 0; k < 8; ++k) {
    int row = rbase + k; if (row > NN - 1) row = NN - 1;
    boff[k] = row * WPR;
    fr[k] = A.f[row];
    float e = fr[k] + A.mg[row];
    mr[k] = fmaxf(e, LK_ALPHA * e);  // lr(f + maxg) = exact row max (lr monotone)
    acc[k] = 0.f; sp[k] = 0.f;
  }

  const int jr = threadIdx.x >> 4;        // 0..15
  const int dc = (threadIdx.x & 15) * 4;  // 0..60

  for (int jt = 0; jt < NWORDS; ++jt) {
    __syncthreads();                      // everyone done reading old whs
    // stage Wh tile (coalesced float4)
#pragma unroll
    for (int q = 0; q < 4; ++q) {
      int j = jr + q * 16;
      int jg = jt * 64 + j;
      float4 v;
      if (jg < NN) v = *(const float4*)(A.wh + (size_t)jg * 64 + dc);
      else         v = make_float4(0.f, 0.f, 0.f, 0.f);
      *(float4*)&whs[j][dc] = v;
    }
    __syncthreads();                      // whs ready

    int jg = jt * 64 + lane;
    float gj = (jg < NN) ? A.g[jg] : 0.f;
    // P tile for this wave's 8 rows (lane = j)
#pragma unroll
    for (int k = 0; k < 8; ++k) {
      u64 word = A.bits[boff[k] + jt];
      float e = fr[k] + gj;
      e = fmaxf(e, LK_ALPHA * e);         // leaky_relu
      float p = ((word >> lane) & 1ull) ? __expf(e - mr[k]) : 0.f;
      sp[k] += p;
      Ps[w][k][lane] = p;
    }
    // Outer-product FMA: lane = d. Same-wave LDS RAW; compiler inserts waits.
#pragma unroll
    for (int j4 = 0; j4 < 16; ++j4) {
      float w0 = whs[4 * j4 + 0][lane];
      float w1 = whs[4 * j4 + 1][lane];
      float w2 = whs[4 * j4 + 2][lane];
      float w3 = whs[4 * j4 + 3][lane];
#pragma unroll
      for (int k = 0; k < 8; ++k) {
        float4 p4 = *(const float4*)&Ps[w][k][4 * j4];
        float a = acc[k];
        a = fmaf(p4.x, w0, a);
        a = fmaf(p4.y, w1, a);
        a = fmaf(p4.z, w2, a);
        a = fmaf(p4.w, w3, a);
        acc[k] = a;
      }
    }
  }

#pragma unroll
  for (int k = 0; k < 8; ++k) {
    int row = rbase + k;
    float s = wsum64(sp[k]);
    float o = acc[k] / s;
    o = (o > 0.f) ? o : expm1f(o);        // elu (alpha=1)
    if (MODE == 1) {                       // row log_softmax over 64 dims
      float mx = wmax64(o);
      float ex = __expf(o - mx);
      float se = wsum64(ex);
      o = (o - mx) - logf(se);
    }
    if (row < NN) A.out[(size_t)row * 64 + lane] = o;
  }
}

// ---------------------------------------------------------------------------
// 5. Attention fusion + MLP head. One wave per node.
// ---------------------------------------------------------------------------
__global__ __launch_bounds__(256) void fuse_kernel(float* __restrict__ out,
                                                   const float* __restrict__ aw1,
                                                   const float* __restrict__ ab1,
                                                   const float* __restrict__ aw2,
                                                   const float* __restrict__ mlpw,
                                                   const float* __restrict__ mlpb) {
  __shared__ float zs[4][64];
  const int w = threadIdx.x >> 6, lane = threadIdx.x & 63;
  const int i = blockIdx.x * 4 + w;

  const float* emb1 = out + OFF_EMB1;
  const float* com1 = out + OFF_COM1;
  const float* com2 = out + OFF_COM2;
  const float* emb2 = out + OFF_EMB2;

  float z0 = emb1[(size_t)i * 64 + lane];
  float z1 = emb2[(size_t)i * 64 + lane];
  float z2 = 0.5f * (com1[(size_t)i * 64 + lane] + com2[(size_t)i * 64 + lane]);
  float zk[3] = {z0, z1, z2};
  float wk[3];
#pragma unroll
  for (int k = 0; k < 3; ++k) {
    zs[w][lane] = zk[k];
    int h = lane & 15;                   // 4 redundant 16-lane groups
    float dot = ab1[h];
    for (int d = 0; d < 64; ++d) dot = fmaf(zs[w][d], aw1[d * 16 + h], dot);
    float c = tanhf(dot) * aw2[h];
#pragma unroll
    for (int off = 1; off < 16; off <<= 1) c += __shfl_xor(c, off);
    wk[k] = c;
  }
  float mw = fmaxf(wk[0], fmaxf(wk[1], wk[2]));
  float e0 = __expf(wk[0] - mw), e1 = __expf(wk[1] - mw), e2 = __expf(wk[2] - mw);
  float s = e0 + e1 + e2;
  float b0 = e0 / s, b1 = e1 / s, b2 = e2 / s;
  float emb = b0 * z0 + b1 * z1 + b2 * z2;
  out[OFF_EMB + (size_t)i * 64 + lane] = emb;
  if (lane == 0) {
    float* bp = out + OFF_BETA + (size_t)i * 3;
    bp[0] = b0; bp[1] = b1; bp[2] = b2;
  }
  zs[w][lane] = emb;
  int c8 = lane & 7;                     // 8 redundant 8-lane groups
  float lg = mlpb[c8];
  for (int d = 0; d < 64; ++d) lg = fmaf(zs[w][d], mlpw[d * 8 + c8], lg);
  float mx = lg;
#pragma unroll
  for (int off = 1; off < 8; off <<= 1) mx = fmaxf(mx, __shfl_xor(mx, off));
  float ex = __expf(lg - mx);
  float se = ex;
#pragma unroll
  for (int off = 1; off < 8; off <<= 1) se += __shfl_xor(se, off);
  float res = lg - mx - logf(se);
  if (lane < 8) out[OFF_OUTPUT + (size_t)i * 8 + lane] = res;
}

// ---------------------------------------------------------------------------
extern "C" void kernel_launch(void* const* d_in, const int* in_sizes, int n_in,
                              void* d_out, int out_size, void* d_ws, size_t ws_size,
                              hipStream_t stream) {
  const float* x   = (const float*)d_in[0];
  const int* sadj  = (const int*)d_in[1];
  const int* fadj  = (const int*)d_in[2];
  // nets: 0 = s1, 1 = s2, 2 = c
  const float* w1[3] = {(const float*)d_in[3], (const float*)d_in[7], (const float*)d_in[11]};
  const float* a1[3] = {(const float*)d_in[4], (const float*)d_in[8], (const float*)d_in[12]};
  const float* w2[3] = {(const float*)d_in[5], (const float*)d_in[9], (const float*)d_in[13]};
  const float* a2[3] = {(const float*)d_in[6], (const float*)d_in[10], (const float*)d_in[14]};
  const float* aw1  = (const float*)d_in[15];
  const float* ab1  = (const float*)d_in[16];
  const float* aw2  = (const float*)d_in[17];
  const float* mlpw = (const float*)d_in[18];
  const float* mlpb = (const float*)d_in[19];
  float* out = (float*)d_out;

  // workspace bump allocator (256B aligned)
  char* p = (char*)d_ws;
  auto alloc = [&](size_t bytes) { char* r = p; p += (bytes + 255) & ~(size_t)255; return r; };
  u64* sbits = (u64*)alloc((size_t)NN * WPR * 8);
  u64* fbits = (u64*)alloc((size_t)NN * WPR * 8);
  float *Wh1[3], *f1[3], *g1[3];
  for (int n = 0; n < 3; ++n) Wh1[n] = (float*)alloc((size_t)NN * 64 * 4);
  for (int n = 0; n < 3; ++n) f1[n] = (float*)alloc(6144 * 4);
  for (int n = 0; n < 3; ++n) g1[n] = (float*)alloc(6144 * 4);
  float *mg1[4], *h1[4], *Wh2[4], *f2[4], *g2[4], *mg2[4];
  for (int c = 0; c < 4; ++c) mg1[c] = (float*)alloc(6144 * 4);
  for (int c = 0; c < 4; ++c) h1[c] = (float*)alloc((size_t)NN * 64 * 4);
  for (int c = 0; c < 4; ++c) Wh2[c] = (float*)alloc((size_t)NN * 64 * 4);
  for (int c = 0; c < 4; ++c) f2[c] = (float*)alloc(6144 * 4);
  for (int c = 0; c < 4; ++c) g2[c] = (float*)alloc(6144 * 4);
  for (int c = 0; c < 4; ++c) mg2[c] = (float*)alloc(6144 * 4);

  // combos: 0 emb1(s1,sadj) 1 com1(c,sadj) 2 com2(c,fadj) 3 emb2(s2,fadj)
  const int cn[4] = {0, 2, 2, 1};
  const u64* cb[4] = {sbits, sbits, fbits, fbits};
  float* cout[4] = {out + OFF_EMB1, out + OFF_COM1, out + OFF_COM2, out + OFF_EMB2};

  pack_kernel<<<dim3(2048), dim3(256), 0, stream>>>(sadj, fadj, sbits, fbits);

  GemmArgs4 ga1;
  for (int n = 0; n < 3; ++n) ga1.a[n] = {x, w1[n], a1[n], Wh1[n], f1[n], g1[n]};
  ga1.a[3] = ga1.a[0];
  gemm_fg_kernel<<<dim3(375, 3), dim3(256), 0, stream>>>(ga1, 512);

  MaxgArgs4 ma1;
  for (int c = 0; c < 4; ++c) ma1.a[c] = {cb[c], g1[cn[c]], mg1[c]};
  maxg_kernel<<<dim3(375, 4), dim3(256), 0, stream>>>(ma1);

  AggArgs4 aa1;
  for (int c = 0; c < 4; ++c) aa1.a[c] = {cb[c], f1[cn[c]], g1[cn[c]], mg1[c], Wh1[cn[c]], h1[c]};
  agg_kernel<0><<<dim3(188, 4), dim3(256), 0, stream>>>(aa1);

  GemmArgs4 ga2;
  for (int c = 0; c < 4; ++c) ga2.a[c] = {h1[c], w2[cn[c]], a2[cn[c]], Wh2[c], f2[c], g2[c]};
  gemm_fg_kernel<<<dim3(375, 4), dim3(256), 0, stream>>>(ga2, 64);

  MaxgArgs4 ma2;
  for (int c = 0; c < 4; ++c) ma2.a[c] = {cb[c], g2[c], mg2[c]};
  maxg_kernel<<<dim3(375, 4), dim3(256), 0, stream>>>(ma2);

  AggArgs4 aa2;
  for (int c = 0; c < 4; ++c) aa2.a[c] = {cb[c], f2[c], g2[c], mg2[c], Wh2[c], cout[c]};
  agg_kernel<1><<<dim3(188, 4), dim3(256), 0, stream>>>(aa2);

  fuse_kernel<<<dim3(1500), dim3(256), 0, stream>>>(out, aw1, ab1, aw2, mlpw, mlpb);
}

// Round 8
// 832.249 us; speedup vs baseline: 2.8054x; 2.8054x over previous
//
#include <hip/hip_runtime.h>
#include <cstdint>
#include <cstddef>

// Problem constants (fixed by reference)
#define NN 6000
#define WPR 96        // u64 words per bitmask row (94 used + 2 pad)
#define NWORDS 94     // ceil(6000/64)
#define LOG2E 1.4426950408889634f

// d_out layout (flat f32, reference tuple order)
#define OFF_OUTPUT 0
#define OFF_BETA   48000
#define OFF_EMB1   66000
#define OFF_COM1   450000
#define OFF_COM2   834000
#define OFF_EMB2   1218000
#define OFF_EMB    1602000

typedef unsigned long long u64;
typedef unsigned int uint;
typedef unsigned short ushort;

typedef __bf16 bf16x8 __attribute__((ext_vector_type(8)));
typedef float f32x4 __attribute__((ext_vector_type(4)));
typedef ushort u16x8 __attribute__((ext_vector_type(8)));

__device__ __forceinline__ float wsum64(float v) {
#pragma unroll
  for (int off = 32; off > 0; off >>= 1) v += __shfl_xor(v, off);
  return v;
}

// round-to-nearest-even f32 -> bf16 (manual, deterministic)
__device__ __forceinline__ ushort bf16rne(float x) {
  uint b = __float_as_uint(x);
  uint r = b + 0x7FFFu + ((b >> 16) & 1u);
  return (ushort)(r >> 16);
}
__device__ __forceinline__ float bf16tof(ushort h) {
  return __uint_as_float((uint)h << 16);
}

// ---------------------------------------------------------------------------
// 1. Pack 0/1 int32 adjacency into bitmasks. One wave -> one u64 word.
// ---------------------------------------------------------------------------
__global__ __launch_bounds__(256) void pack_kernel(const int* __restrict__ sadj,
                                                   const int* __restrict__ fadj,
                                                   u64* __restrict__ sbits,
                                                   u64* __restrict__ fbits) {
  const int lane = threadIdx.x & 63;
  const int wid = (blockIdx.x * 256 + threadIdx.x) >> 6;
  const int nw = (gridDim.x * 256) >> 6;
  const int per_mat = NN * WPR;
  for (int t = wid; t < 2 * per_mat; t += nw) {
    int m = t / per_mat;
    int rem = t - m * per_mat;
    int row = rem / WPR;
    int wi = rem - row * WPR;
    const int* adj = m ? fadj : sadj;
    int j = wi * 64 + lane;
    int pred = 0;
    if (j < NN) pred = (adj[(size_t)row * NN + j] != 0);
    u64 mask = __ballot(pred);
    if (lane == 0) (m ? fbits : sbits)[row * WPR + wi] = mask;
  }
}

// ---------------------------------------------------------------------------
// 2. Wh = X @ W  (M=6000, N=64, K runtime), fused f/g = (Wh@a[:64|64:]) * log2e
// ---------------------------------------------------------------------------
struct GemmArgs { const float* X; const float* W; const float* A; float* wh; float* f; float* g; };
struct GemmArgs4 { GemmArgs a[4]; };

__global__ __launch_bounds__(256) void gemm_fg_kernel(GemmArgs4 P, int K) {
  GemmArgs A = P.a[blockIdx.y];
  const int w = threadIdx.x >> 6, lane = threadIdx.x & 63;
  const int r0 = blockIdx.x * 16 + w * 4;
  float acc[4] = {0.f, 0.f, 0.f, 0.f};
  const float* X0 = A.X + (size_t)r0 * K;
  for (int k = 0; k < K; k += 4) {
    float xa[4][4];
    *(float4*)xa[0] = *(const float4*)(X0 + k);
    *(float4*)xa[1] = *(const float4*)(X0 + K + k);
    *(float4*)xa[2] = *(const float4*)(X0 + 2 * (size_t)K + k);
    *(float4*)xa[3] = *(const float4*)(X0 + 3 * (size_t)K + k);
#pragma unroll
    for (int kk = 0; kk < 4; ++kk) {
      float wv = A.W[(size_t)(k + kk) * 64 + lane];
#pragma unroll
      for (int r = 0; r < 4; ++r) acc[r] = fmaf(xa[r][kk], wv, acc[r]);
    }
  }
  float af = A.A[lane], ag = A.A[64 + lane];
#pragma unroll
  for (int r = 0; r < 4; ++r) {
    A.wh[(size_t)(r0 + r) * 64 + lane] = acc[r];
    float pf = wsum64(acc[r] * af);
    float pg = wsum64(acc[r] * ag);
    if (lane == 0) { A.f[r0 + r] = pf * LOG2E; A.g[r0 + r] = pg * LOG2E; }
  }
}

// ---------------------------------------------------------------------------
// 3. Build MFMA-fragment-ready bf16 hi/lo tiles of Wh^T.
//    frag unit index (jt*8 + fi)*64 + lane, fi = k0*4 + n0; element i holds
//    Wh[j = jt*64 + k0*32 + (lane>>4)*8 + i][d = n0*16 + (lane&15)]; j>=NN -> 0.
// ---------------------------------------------------------------------------
struct TransArgs { const float* wh; ushort* bhi; ushort* blo; };
struct TransArgs4 { TransArgs a[4]; };

__global__ __launch_bounds__(256) void trans_kernel(TransArgs4 P) {
  TransArgs A = P.a[blockIdx.y];
  const int jt = blockIdx.x;
  __shared__ float t[64][69];          // [j_local][d], pad 69 for conflict spread
  const int tid = threadIdx.x;
#pragma unroll
  for (int it = 0; it < 4; ++it) {
    int jl = (tid >> 4) + it * 16;
    int j = jt * 64 + jl;
    float4 v = make_float4(0.f, 0.f, 0.f, 0.f);
    if (j < NN) v = *(const float4*)(A.wh + (size_t)j * 64 + (tid & 15) * 4);
    int d0 = (tid & 15) * 4;
    t[jl][d0] = v.x; t[jl][d0 + 1] = v.y; t[jl][d0 + 2] = v.z; t[jl][d0 + 3] = v.w;
  }
  __syncthreads();
  const int w = tid >> 6, lane = tid & 63, q = lane >> 4, m16 = lane & 15;
#pragma unroll
  for (int fi0 = 0; fi0 < 2; ++fi0) {
    int fi = w + fi0 * 4;              // 0..7 ; k0 = fi>>2, n0 = fi&3
    int k0 = fi >> 2, n0 = fi & 3;
    u16x8 hv, lv;
#pragma unroll
    for (int i = 0; i < 8; ++i) {
      float x = t[k0 * 32 + q * 8 + i][n0 * 16 + m16];
      ushort h = bf16rne(x);
      hv[i] = h;
      lv[i] = bf16rne(x - bf16tof(h));
    }
    size_t off = ((size_t)jt * 8 + fi) * 64 + lane;   // in u16x8 units
    *(u16x8*)(A.bhi + off * 8) = hv;
    *(u16x8*)(A.blo + off * 8) = lv;
  }
}

// ---------------------------------------------------------------------------
// 4. Masked-softmax aggregation via MFMA (bf16 hi/lo 3-pass):
//      out[i,:] = softmax_mask(leakyrelu(f_i+g_j)) @ Wh
//    Block: 512 thr = 8 waves = 4 row-groups x 2 j-halves. M=64 rows/block.
//    Softmax uses no max-shift (scores bounded); exp folded to exp2 upstream.
//    MODE 0: elu epilogue.  MODE 1: elu + row log_softmax.
// ---------------------------------------------------------------------------
struct Agg2Args { const u64* bits; const float* f; const float* g;
                  const ushort* bhi; const ushort* blo; float* out; };
struct Agg2Args4 { Agg2Args a[4]; };

template <int MODE>
__global__ __launch_bounds__(512) void agg2_kernel(Agg2Args4 P) {
  const int bid = blockIdx.x;
  const int combo = (bid & 7) >> 1;                 // XCD-pair per combo
  const int mt = ((bid >> 3) << 1) | (bid & 1);     // 0..93 row-tile
  Agg2Args A = P.a[combo];
  const int w = threadIdx.x >> 6, lane = threadIdx.x & 63;
  const int rg = w & 3, jh = w >> 2;
  const int q = lane >> 4, m16 = lane & 15;
  const int row = mt * 64 + rg * 16 + m16;
  const int rc = row < NN ? row : NN - 1;
  const float fr = A.f[rc];
  const u64* brow = A.bits + (size_t)rc * WPR;

  f32x4 acc[4] = {{0,0,0,0},{0,0,0,0},{0,0,0,0},{0,0,0,0}};
  float sp = 0.f;

  for (int jt = jh; jt < NWORDS; jt += 2) {
    u64 word = brow[jt];
    // ---- A fragments (P): lane-local, no LDS, no redundancy
    u16x8 ph[2], pl[2];
#pragma unroll
    for (int k0 = 0; k0 < 2; ++k0) {
      uint byt = (uint)(word >> (k0 * 32 + q * 8)) & 0xFFu;
      const float* gp = A.g + jt * 64 + k0 * 32 + q * 8;
      float4 gA = *(const float4*)gp;
      float4 gB = *(const float4*)(gp + 4);
      float ge[8] = {gA.x, gA.y, gA.z, gA.w, gB.x, gB.y, gB.z, gB.w};
      u16x8 hv, lv;
#pragma unroll
      for (int i = 0; i < 8; ++i) {
        float e = fr + ge[i];
        float lr = fmaxf(e, 0.2f * e);              // leaky_relu (log2 domain)
        float p = exp2f(lr);
        p = (byt & (1u << i)) ? p : 0.f;
        sp += p;
        ushort h = bf16rne(p);
        hv[i] = h;
        lv[i] = bf16rne(p - bf16tof(h));
      }
      ph[k0] = hv; pl[k0] = lv;
    }
    // ---- B fragments (coalesced dwordx4 from frag-ready global) + MFMA
    const u16x8* BH = (const u16x8*)A.bhi + ((size_t)jt * 8) * 64 + lane;
    const u16x8* BL = (const u16x8*)A.blo + ((size_t)jt * 8) * 64 + lane;
    bf16x8 a0h = __builtin_bit_cast(bf16x8, ph[0]);
    bf16x8 a1h = __builtin_bit_cast(bf16x8, ph[1]);
    bf16x8 a0l = __builtin_bit_cast(bf16x8, pl[0]);
    bf16x8 a1l = __builtin_bit_cast(bf16x8, pl[1]);
#pragma unroll
    for (int n0 = 0; n0 < 4; ++n0) {
      u16x8 bh0 = BH[n0 * 64], bh1 = BH[(4 + n0) * 64];
      u16x8 bl0 = BL[n0 * 64], bl1 = BL[(4 + n0) * 64];
      bf16x8 b0h = __builtin_bit_cast(bf16x8, bh0);
      bf16x8 b1h = __builtin_bit_cast(bf16x8, bh1);
      bf16x8 b0l = __builtin_bit_cast(bf16x8, bl0);
      bf16x8 b1l = __builtin_bit_cast(bf16x8, bl1);
      acc[n0] = __builtin_amdgcn_mfma_f32_16x16x32_bf16(a0h, b0h, acc[n0], 0, 0, 0);
      acc[n0] = __builtin_amdgcn_mfma_f32_16x16x32_bf16(a1h, b1h, acc[n0], 0, 0, 0);
      acc[n0] = __builtin_amdgcn_mfma_f32_16x16x32_bf16(a0h, b0l, acc[n0], 0, 0, 0);
      acc[n0] = __builtin_amdgcn_mfma_f32_16x16x32_bf16(a1h, b1l, acc[n0], 0, 0, 0);
      acc[n0] = __builtin_amdgcn_mfma_f32_16x16x32_bf16(a0l, b0h, acc[n0], 0, 0, 0);
      acc[n0] = __builtin_amdgcn_mfma_f32_16x16x32_bf16(a1l, b1h, acc[n0], 0, 0, 0);
    }
  }

  // row-total of sp for this j-half (rows indexed by m16; 4 lanes share a row)
  sp += __shfl_xor(sp, 16);
  sp += __shfl_xor(sp, 32);

  // ---- combine the two j-halves via LDS, epilogue on jh==1 waves
  __shared__ float cb[64][68];
  __shared__ float spb[64];
  if (jh == 0) {
#pragma unroll
    for (int n0 = 0; n0 < 4; ++n0)
#pragma unroll
      for (int r = 0; r < 4; ++r)
        cb[rg * 16 + q * 4 + r][n0 * 16 + m16] = acc[n0][r];
    if (lane < 16) spb[rg * 16 + lane] = sp;
  }
  __syncthreads();
  if (jh == 1) {
    if (lane < 16) spb[rg * 16 + lane] += sp;
  }
  __syncthreads();
  if (jh == 1) {
    float ot[4][4];   // [n0][r]
#pragma unroll
    for (int r = 0; r < 4; ++r) {
      float sprow = spb[rg * 16 + q * 4 + r];
#pragma unroll
      for (int n0 = 0; n0 < 4; ++n0) {
        float o = acc[n0][r] + cb[rg * 16 + q * 4 + r][n0 * 16 + m16];
        o /= sprow;
        ot[n0][r] = (o > 0.f) ? o : expm1f(o);      // elu
      }
    }
#pragma unroll
    for (int r = 0; r < 4; ++r) {
      int orow = mt * 64 + rg * 16 + q * 4 + r;
      float v0 = ot[0][r], v1 = ot[1][r], v2 = ot[2][r], v3 = ot[3][r];
      if (MODE == 1) {                               // log_softmax over 64 dims
        float mx = fmaxf(fmaxf(v0, v1), fmaxf(v2, v3));
#pragma unroll
        for (int off = 1; off < 16; off <<= 1) mx = fmaxf(mx, __shfl_xor(mx, off));
        float se = __expf(v0 - mx) + __expf(v1 - mx) + __expf(v2 - mx) + __expf(v3 - mx);
#pragma unroll
        for (int off = 1; off < 16; off <<= 1) se += __shfl_xor(se, off);
        float lse = mx + logf(se);
        v0 -= lse; v1 -= lse; v2 -= lse; v3 -= lse;
      }
      if (orow < NN) {
        float* op = A.out + (size_t)orow * 64 + m16;
        op[0] = v0; op[16] = v1; op[32] = v2; op[48] = v3;
      }
    }
  }
}

// ---------------------------------------------------------------------------
// 5. Attention fusion + MLP head. One wave per node.
// ---------------------------------------------------------------------------
__global__ __launch_bounds__(256) void fuse_kernel(float* __restrict__ out,
                                                   const float* __restrict__ aw1,
                                                   const float* __restrict__ ab1,
                                                   const float* __restrict__ aw2,
                                                   const float* __restrict__ mlpw,
                                                   const float* __restrict__ mlpb) {
  __shared__ float zs[4][64];
  const int w = threadIdx.x >> 6, lane = threadIdx.x & 63;
  const int i = blockIdx.x * 4 + w;

  const float* emb1 = out + OFF_EMB1;
  const float* com1 = out + OFF_COM1;
  const float* com2 = out + OFF_COM2;
  const float* emb2 = out + OFF_EMB2;

  float z0 = emb1[(size_t)i * 64 + lane];
  float z1 = emb2[(size_t)i * 64 + lane];
  float z2 = 0.5f * (com1[(size_t)i * 64 + lane] + com2[(size_t)i * 64 + lane]);
  float zk[3] = {z0, z1, z2};
  float wk[3];
#pragma unroll
  for (int k = 0; k < 3; ++k) {
    zs[w][lane] = zk[k];
    int h = lane & 15;
    float dot = ab1[h];
    for (int d = 0; d < 64; ++d) dot = fmaf(zs[w][d], aw1[d * 16 + h], dot);
    float c = tanhf(dot) * aw2[h];
#pragma unroll
    for (int off = 1; off < 16; off <<= 1) c += __shfl_xor(c, off);
    wk[k] = c;
  }
  float mw = fmaxf(wk[0], fmaxf(wk[1], wk[2]));
  float e0 = __expf(wk[0] - mw), e1 = __expf(wk[1] - mw), e2 = __expf(wk[2] - mw);
  float s = e0 + e1 + e2;
  float b0 = e0 / s, b1 = e1 / s, b2 = e2 / s;
  float emb = b0 * z0 + b1 * z1 + b2 * z2;
  out[OFF_EMB + (size_t)i * 64 + lane] = emb;
  if (lane == 0) {
    float* bp = out + OFF_BETA + (size_t)i * 3;
    bp[0] = b0; bp[1] = b1; bp[2] = b2;
  }
  zs[w][lane] = emb;
  int c8 = lane & 7;
  float lg = mlpb[c8];
  for (int d = 0; d < 64; ++d) lg = fmaf(zs[w][d], mlpw[d * 8 + c8], lg);
  float mx = lg;
#pragma unroll
  for (int off = 1; off < 8; off <<= 1) mx = fmaxf(mx, __shfl_xor(mx, off));
  float ex = __expf(lg - mx);
  float se = ex;
#pragma unroll
  for (int off = 1; off < 8; off <<= 1) se += __shfl_xor(se, off);
  float res = lg - mx - logf(se);
  if (lane < 8) out[OFF_OUTPUT + (size_t)i * 8 + lane] = res;
}

// ---------------------------------------------------------------------------
extern "C" void kernel_launch(void* const* d_in, const int* in_sizes, int n_in,
                              void* d_out, int out_size, void* d_ws, size_t ws_size,
                              hipStream_t stream) {
  const float* x   = (const float*)d_in[0];
  const int* sadj  = (const int*)d_in[1];
  const int* fadj  = (const int*)d_in[2];
  // nets: 0 = s1, 1 = s2, 2 = c
  const float* w1[3] = {(const float*)d_in[3], (const float*)d_in[7], (const float*)d_in[11]};
  const float* a1[3] = {(const float*)d_in[4], (const float*)d_in[8], (const float*)d_in[12]};
  const float* w2[3] = {(const float*)d_in[5], (const float*)d_in[9], (const float*)d_in[13]};
  const float* a2[3] = {(const float*)d_in[6], (const float*)d_in[10], (const float*)d_in[14]};
  const float* aw1  = (const float*)d_in[15];
  const float* ab1  = (const float*)d_in[16];
  const float* aw2  = (const float*)d_in[17];
  const float* mlpw = (const float*)d_in[18];
  const float* mlpb = (const float*)d_in[19];
  float* out = (float*)d_out;

  // workspace bump allocator (256B aligned)
  char* p = (char*)d_ws;
  auto alloc = [&](size_t bytes) { char* r = p; p += (bytes + 255) & ~(size_t)255; return r; };
  const size_t FRAG_ELEMS = (size_t)NWORDS * 8 * 64 * 8;   // ushort count (~770KB)
  u64* sbits = (u64*)alloc((size_t)NN * WPR * 8);
  u64* fbits = (u64*)alloc((size_t)NN * WPR * 8);
  float *Wh1[3], *f1[3], *g1[3];
  ushort *hi1[3], *lo1[3];
  for (int n = 0; n < 3; ++n) Wh1[n] = (float*)alloc((size_t)NN * 64 * 4);
  for (int n = 0; n < 3; ++n) f1[n] = (float*)alloc(6144 * 4);
  for (int n = 0; n < 3; ++n) g1[n] = (float*)alloc(6144 * 4);
  for (int n = 0; n < 3; ++n) { hi1[n] = (ushort*)alloc(FRAG_ELEMS * 2); lo1[n] = (ushort*)alloc(FRAG_ELEMS * 2); }
  float *h1[4], *Wh2[4], *f2[4], *g2[4];
  ushort *hi2[4], *lo2[4];
  for (int c = 0; c < 4; ++c) h1[c] = (float*)alloc((size_t)NN * 64 * 4);
  for (int c = 0; c < 4; ++c) Wh2[c] = (float*)alloc((size_t)NN * 64 * 4);
  for (int c = 0; c < 4; ++c) f2[c] = (float*)alloc(6144 * 4);
  for (int c = 0; c < 4; ++c) g2[c] = (float*)alloc(6144 * 4);
  for (int c = 0; c < 4; ++c) { hi2[c] = (ushort*)alloc(FRAG_ELEMS * 2); lo2[c] = (ushort*)alloc(FRAG_ELEMS * 2); }

  // combos: 0 emb1(s1,sadj) 1 com1(c,sadj) 2 com2(c,fadj) 3 emb2(s2,fadj)
  const int cn[4] = {0, 2, 2, 1};
  const u64* cb[4] = {sbits, sbits, fbits, fbits};
  float* cout[4] = {out + OFF_EMB1, out + OFF_COM1, out + OFF_COM2, out + OFF_EMB2};

  pack_kernel<<<dim3(2048), dim3(256), 0, stream>>>(sadj, fadj, sbits, fbits);

  GemmArgs4 ga1;
  for (int n = 0; n < 3; ++n) ga1.a[n] = {x, w1[n], a1[n], Wh1[n], f1[n], g1[n]};
  ga1.a[3] = ga1.a[0];
  gemm_fg_kernel<<<dim3(375, 3), dim3(256), 0, stream>>>(ga1, 512);

  TransArgs4 ta1;
  for (int n = 0; n < 3; ++n) ta1.a[n] = {Wh1[n], hi1[n], lo1[n]};
  ta1.a[3] = ta1.a[0];
  trans_kernel<<<dim3(NWORDS, 3), dim3(256), 0, stream>>>(ta1);

  Agg2Args4 aa1;
  for (int c = 0; c < 4; ++c) aa1.a[c] = {cb[c], f1[cn[c]], g1[cn[c]], hi1[cn[c]], lo1[cn[c]], h1[c]};
  agg2_kernel<0><<<dim3(376), dim3(512), 0, stream>>>(aa1);

  GemmArgs4 ga2;
  for (int c = 0; c < 4; ++c) ga2.a[c] = {h1[c], w2[cn[c]], a2[cn[c]], Wh2[c], f2[c], g2[c]};
  gemm_fg_kernel<<<dim3(375, 4), dim3(256), 0, stream>>>(ga2, 64);

  TransArgs4 ta2;
  for (int c = 0; c < 4; ++c) ta2.a[c] = {Wh2[c], hi2[c], lo2[c]};
  trans_kernel<<<dim3(NWORDS, 4), dim3(256), 0, stream>>>(ta2);

  Agg2Args4 aa2;
  for (int c = 0; c < 4; ++c) aa2.a[c] = {cb[c], f2[c], g2[c], hi2[c], lo2[c], cout[c]};
  agg2_kernel<1><<<dim3(376), dim3(512), 0, stream>>>(aa2);

  fuse_kernel<<<dim3(1500), dim3(256), 0, stream>>>(out, aw1, ab1, aw2, mlpw, mlpb);
}

// Round 11
// 745.884 us; speedup vs baseline: 3.1302x; 1.1158x over previous
//
#include <hip/hip_runtime.h>
#include <cstdint>
#include <cstddef>

// Problem constants (fixed by reference)
#define NN 6000
#define WPR 96        // u64 words per bitmask row (94 used + 2 pad)
#define NWORDS 94     // ceil(6000/64)
#define LOG2E 1.4426950408889634f

// d_out layout (flat f32, reference tuple order)
#define OFF_OUTPUT 0
#define OFF_BETA   48000
#define OFF_EMB1   66000
#define OFF_COM1   450000
#define OFF_COM2   834000
#define OFF_EMB2   1218000
#define OFF_EMB    1602000

typedef unsigned long long u64;
typedef unsigned int uint;
typedef unsigned short ushort;
typedef unsigned char uchar;

typedef __bf16 bf16x8 __attribute__((ext_vector_type(8)));
typedef float f32x4 __attribute__((ext_vector_type(4)));
typedef ushort u16x8 __attribute__((ext_vector_type(8)));

__device__ __forceinline__ float wsum64(float v) {
#pragma unroll
  for (int off = 32; off > 0; off >>= 1) v += __shfl_xor(v, off);
  return v;
}

// round-to-nearest-even f32 -> bf16 (manual, deterministic)
__device__ __forceinline__ ushort bf16rne(float x) {
  uint b = __float_as_uint(x);
  uint r = b + 0x7FFFu + ((b >> 16) & 1u);
  return (ushort)(r >> 16);
}
__device__ __forceinline__ float bf16tof(ushort h) {
  return __uint_as_float((uint)h << 16);
}

// ---------------------------------------------------------------------------
// 1. Pack 0/1 int32 adjacency into bitmask bytes (u64-word compatible).
//    One wave per row; lane builds one byte (8 j's) from two int4 loads.
//    Byte b of row covers j = 8b..8b+7; little-endian bytes form the u64
//    words the consumer reads. 750 real bytes, 768 stored (pad = 0).
// ---------------------------------------------------------------------------
__global__ __launch_bounds__(256) void pack_kernel(const int* __restrict__ sadj,
                                                   const int* __restrict__ fadj,
                                                   u64* __restrict__ sbits,
                                                   u64* __restrict__ fbits) {
  const int lane = threadIdx.x & 63;
  const int wid = (blockIdx.x * 256 + threadIdx.x) >> 6;   // 0..11999
  const int m = wid >= NN;
  const int row = m ? wid - NN : wid;
  const int* arow = (m ? fadj : sadj) + (size_t)row * NN;
  uchar* brow = (uchar*)(m ? fbits : sbits) + (size_t)row * (WPR * 8);
#pragma unroll
  for (int it = 0; it < 12; ++it) {          // 12*64 = 768 bytes
    int byte = it * 64 + lane;
    uint b = 0;
    if (byte < 750) {
      const int4* p4 = (const int4*)(arow + byte * 8);
      int4 v0 = p4[0], v1 = p4[1];
      b = (uint)(v0.x != 0) | ((uint)(v0.y != 0) << 1) |
          ((uint)(v0.z != 0) << 2) | ((uint)(v0.w != 0) << 3) |
          ((uint)(v1.x != 0) << 4) | ((uint)(v1.y != 0) << 5) |
          ((uint)(v1.z != 0) << 6) | ((uint)(v1.w != 0) << 7);
    }
    brow[byte] = (uchar)b;
  }
}

// ---------------------------------------------------------------------------
// 2. Wh = X @ W  (M=6000, N=64, K runtime), fused f/g = (Wh@a[:64|64:]) * log2e
//    X tile (16 rows, contiguous 16*K floats) staged in LDS coalesced;
//    compute reads X as LDS broadcasts (free), W coalesced from L2.
// ---------------------------------------------------------------------------
struct GemmArgs { const float* X; const float* W; const float* A; float* wh; float* f; float* g; };
struct GemmArgs4 { GemmArgs a[4]; };

__global__ __launch_bounds__(256) void gemm_fg_kernel(GemmArgs4 P, int K) {
  GemmArgs A = P.a[blockIdx.y];
  __shared__ float xs[16 * 512];             // max K=512 -> 32KB
  const int tid = threadIdx.x;
  const int w = tid >> 6, lane = tid & 63;
  const int r0b = blockIdx.x * 16;
  const float* Xb = A.X + (size_t)r0b * K;   // 16 contiguous rows
  const int nf4 = (16 * K) >> 2;
  for (int i = tid; i < nf4; i += 256)
    *(float4*)&xs[i * 4] = *(const float4*)(Xb + (size_t)i * 4);
  __syncthreads();

  const int r0 = w * 4;
  float acc[4] = {0.f, 0.f, 0.f, 0.f};
  for (int k = 0; k < K; k += 4) {
    float xa[4][4];
    *(float4*)xa[0] = *(const float4*)&xs[(r0 + 0) * K + k];
    *(float4*)xa[1] = *(const float4*)&xs[(r0 + 1) * K + k];
    *(float4*)xa[2] = *(const float4*)&xs[(r0 + 2) * K + k];
    *(float4*)xa[3] = *(const float4*)&xs[(r0 + 3) * K + k];
#pragma unroll
    for (int kk = 0; kk < 4; ++kk) {
      float wv = A.W[(size_t)(k + kk) * 64 + lane];
#pragma unroll
      for (int r = 0; r < 4; ++r) acc[r] = fmaf(xa[r][kk], wv, acc[r]);
    }
  }
  float af = A.A[lane], ag = A.A[64 + lane];
#pragma unroll
  for (int r = 0; r < 4; ++r) {
    A.wh[(size_t)(r0b + r0 + r) * 64 + lane] = acc[r];
    float pf = wsum64(acc[r] * af);
    float pg = wsum64(acc[r] * ag);
    if (lane == 0) { A.f[r0b + r0 + r] = pf * LOG2E; A.g[r0b + r0 + r] = pg * LOG2E; }
  }
}

// ---------------------------------------------------------------------------
// 3. Build MFMA-fragment-ready bf16 hi/lo tiles of Wh^T.
//    frag unit index (jt*8 + fi)*64 + lane, fi = k0*4 + n0; element i holds
//    Wh[j = jt*64 + k0*32 + (lane>>4)*8 + i][d = n0*16 + (lane&15)]; j>=NN -> 0.
// ---------------------------------------------------------------------------
struct TransArgs { const float* wh; ushort* bhi; ushort* blo; };
struct TransArgs4 { TransArgs a[4]; };

__global__ __launch_bounds__(256) void trans_kernel(TransArgs4 P) {
  TransArgs A = P.a[blockIdx.y];
  const int jt = blockIdx.x;
  __shared__ float t[64][69];          // [j_local][d], pad 69 for conflict spread
  const int tid = threadIdx.x;
#pragma unroll
  for (int it = 0; it < 4; ++it) {
    int jl = (tid >> 4) + it * 16;
    int j = jt * 64 + jl;
    float4 v = make_float4(0.f, 0.f, 0.f, 0.f);
    if (j < NN) v = *(const float4*)(A.wh + (size_t)j * 64 + (tid & 15) * 4);
    int d0 = (tid & 15) * 4;
    t[jl][d0] = v.x; t[jl][d0 + 1] = v.y; t[jl][d0 + 2] = v.z; t[jl][d0 + 3] = v.w;
  }
  __syncthreads();
  const int w = tid >> 6, lane = tid & 63, q = lane >> 4, m16 = lane & 15;
#pragma unroll
  for (int fi0 = 0; fi0 < 2; ++fi0) {
    int fi = w + fi0 * 4;              // 0..7 ; k0 = fi>>2, n0 = fi&3
    int k0 = fi >> 2, n0 = fi & 3;
    u16x8 hv, lv;
#pragma unroll
    for (int i = 0; i < 8; ++i) {
      float x = t[k0 * 32 + q * 8 + i][n0 * 16 + m16];
      ushort h = bf16rne(x);
      hv[i] = h;
      lv[i] = bf16rne(x - bf16tof(h));
    }
    size_t off = ((size_t)jt * 8 + fi) * 64 + lane;   // in u16x8 units
    *(u16x8*)(A.bhi + off * 8) = hv;
    *(u16x8*)(A.blo + off * 8) = lv;
  }
}

// ---------------------------------------------------------------------------
// 4. Masked-softmax aggregation via MFMA (bf16 hi/lo 3-pass) — round-8 HW-
//    validated version (512 thr = 8 waves = 4 row-groups x 2 j-halves,
//    M=64 rows/block, per-element RNE encode).
//    MODE 0: elu epilogue.  MODE 1: elu + row log_softmax.
// ---------------------------------------------------------------------------
struct Agg2Args { const u64* bits; const float* f; const float* g;
                  const ushort* bhi; const ushort* blo; float* out; };
struct Agg2Args4 { Agg2Args a[4]; };

template <int MODE>
__global__ __launch_bounds__(512) void agg2_kernel(Agg2Args4 P) {
  const int bid = blockIdx.x;
  const int combo = (bid & 7) >> 1;                 // XCD-pair per combo
  const int mt = ((bid >> 3) << 1) | (bid & 1);     // 0..93 row-tile
  Agg2Args A = P.a[combo];
  const int w = threadIdx.x >> 6, lane = threadIdx.x & 63;
  const int rg = w & 3, jh = w >> 2;
  const int q = lane >> 4, m16 = lane & 15;
  const int row = mt * 64 + rg * 16 + m16;
  const int rc = row < NN ? row : NN - 1;
  const float fr = A.f[rc];
  const u64* brow = A.bits + (size_t)rc * WPR;

  f32x4 acc[4] = {{0,0,0,0},{0,0,0,0},{0,0,0,0},{0,0,0,0}};
  float sp = 0.f;

  for (int jt = jh; jt < NWORDS; jt += 2) {
    u64 word = brow[jt];
    // ---- A fragments (P): lane-local, no LDS, no redundancy
    u16x8 ph[2], pl[2];
#pragma unroll
    for (int k0 = 0; k0 < 2; ++k0) {
      uint byt = (uint)(word >> (k0 * 32 + q * 8)) & 0xFFu;
      const float* gp = A.g + jt * 64 + k0 * 32 + q * 8;
      float4 gA = *(const float4*)gp;
      float4 gB = *(const float4*)(gp + 4);
      float ge[8] = {gA.x, gA.y, gA.z, gA.w, gB.x, gB.y, gB.z, gB.w};
      u16x8 hv, lv;
#pragma unroll
      for (int i = 0; i < 8; ++i) {
        float e = fr + ge[i];
        float lr = fmaxf(e, 0.2f * e);              // leaky_relu (log2 domain)
        float p = exp2f(lr);
        p = (byt & (1u << i)) ? p : 0.f;
        sp += p;
        ushort h = bf16rne(p);
        hv[i] = h;
        lv[i] = bf16rne(p - bf16tof(h));
      }
      ph[k0] = hv; pl[k0] = lv;
    }
    // ---- B fragments (coalesced dwordx4 from frag-ready global) + MFMA
    const u16x8* BH = (const u16x8*)A.bhi + ((size_t)jt * 8) * 64 + lane;
    const u16x8* BL = (const u16x8*)A.blo + ((size_t)jt * 8) * 64 + lane;
    bf16x8 a0h = __builtin_bit_cast(bf16x8, ph[0]);
    bf16x8 a1h = __builtin_bit_cast(bf16x8, ph[1]);
    bf16x8 a0l = __builtin_bit_cast(bf16x8, pl[0]);
    bf16x8 a1l = __builtin_bit_cast(bf16x8, pl[1]);
#pragma unroll
    for (int n0 = 0; n0 < 4; ++n0) {
      u16x8 bh0 = BH[n0 * 64], bh1 = BH[(4 + n0) * 64];
      u16x8 bl0 = BL[n0 * 64], bl1 = BL[(4 + n0) * 64];
      bf16x8 b0h = __builtin_bit_cast(bf16x8, bh0);
      bf16x8 b1h = __builtin_bit_cast(bf16x8, bh1);
      bf16x8 b0l = __builtin_bit_cast(bf16x8, bl0);
      bf16x8 b1l = __builtin_bit_cast(bf16x8, bl1);
      acc[n0] = __builtin_amdgcn_mfma_f32_16x16x32_bf16(a0h, b0h, acc[n0], 0, 0, 0);
      acc[n0] = __builtin_amdgcn_mfma_f32_16x16x32_bf16(a1h, b1h, acc[n0], 0, 0, 0);
      acc[n0] = __builtin_amdgcn_mfma_f32_16x16x32_bf16(a0h, b0l, acc[n0], 0, 0, 0);
      acc[n0] = __builtin_amdgcn_mfma_f32_16x16x32_bf16(a1h, b1l, acc[n0], 0, 0, 0);
      acc[n0] = __builtin_amdgcn_mfma_f32_16x16x32_bf16(a0l, b0h, acc[n0], 0, 0, 0);
      acc[n0] = __builtin_amdgcn_mfma_f32_16x16x32_bf16(a1l, b1h, acc[n0], 0, 0, 0);
    }
  }

  // row-total of sp for this j-half (rows indexed by m16; 4 lanes share a row)
  sp += __shfl_xor(sp, 16);
  sp += __shfl_xor(sp, 32);

  // ---- combine the two j-halves via LDS, epilogue on jh==1 waves
  __shared__ float cb[64][68];
  __shared__ float spb[64];
  if (jh == 0) {
#pragma unroll
    for (int n0 = 0; n0 < 4; ++n0)
#pragma unroll
      for (int r = 0; r < 4; ++r)
        cb[rg * 16 + q * 4 + r][n0 * 16 + m16] = acc[n0][r];
    if (lane < 16) spb[rg * 16 + lane] = sp;
  }
  __syncthreads();
  if (jh == 1) {
    if (lane < 16) spb[rg * 16 + lane] += sp;
  }
  __syncthreads();
  if (jh == 1) {
    float ot[4][4];   // [n0][r]
#pragma unroll
    for (int r = 0; r < 4; ++r) {
      float sprow = spb[rg * 16 + q * 4 + r];
#pragma unroll
      for (int n0 = 0; n0 < 4; ++n0) {
        float o = acc[n0][r] + cb[rg * 16 + q * 4 + r][n0 * 16 + m16];
        o /= sprow;
        ot[n0][r] = (o > 0.f) ? o : expm1f(o);      // elu
      }
    }
#pragma unroll
    for (int r = 0; r < 4; ++r) {
      int orow = mt * 64 + rg * 16 + q * 4 + r;
      float v0 = ot[0][r], v1 = ot[1][r], v2 = ot[2][r], v3 = ot[3][r];
      if (MODE == 1) {                               // log_softmax over 64 dims
        float mx = fmaxf(fmaxf(v0, v1), fmaxf(v2, v3));
#pragma unroll
        for (int off = 1; off < 16; off <<= 1) mx = fmaxf(mx, __shfl_xor(mx, off));
        float se = __expf(v0 - mx) + __expf(v1 - mx) + __expf(v2 - mx) + __expf(v3 - mx);
#pragma unroll
        for (int off = 1; off < 16; off <<= 1) se += __shfl_xor(se, off);
        float lse = mx + logf(se);
        v0 -= lse; v1 -= lse; v2 -= lse; v3 -= lse;
      }
      if (orow < NN) {
        float* op = A.out + (size_t)orow * 64 + m16;
        op[0] = v0; op[16] = v1; op[32] = v2; op[48] = v3;
      }
    }
  }
}

// ---------------------------------------------------------------------------
// 5. Attention fusion + MLP head. One wave per node.
// ---------------------------------------------------------------------------
__global__ __launch_bounds__(256) void fuse_kernel(float* __restrict__ out,
                                                   const float* __restrict__ aw1,
                                                   const float* __restrict__ ab1,
                                                   const float* __restrict__ aw2,
                                                   const float* __restrict__ mlpw,
                                                   const float* __restrict__ mlpb) {
  __shared__ float zs[4][64];
  const int w = threadIdx.x >> 6, lane = threadIdx.x & 63;
  const int i = blockIdx.x * 4 + w;

  const float* emb1 = out + OFF_EMB1;
  const float* com1 = out + OFF_COM1;
  const float* com2 = out + OFF_COM2;
  const float* emb2 = out + OFF_EMB2;

  float z0 = emb1[(size_t)i * 64 + lane];
  float z1 = emb2[(size_t)i * 64 + lane];
  float z2 = 0.5f * (com1[(size_t)i * 64 + lane] + com2[(size_t)i * 64 + lane]);
  float zk[3] = {z0, z1, z2};
  float wk[3];
#pragma unroll
  for (int k = 0; k < 3; ++k) {
    zs[w][lane] = zk[k];
    int h = lane & 15;
    float dot = ab1[h];
    for (int d = 0; d < 64; ++d) dot = fmaf(zs[w][d], aw1[d * 16 + h], dot);
    float c = tanhf(dot) * aw2[h];
#pragma unroll
    for (int off = 1; off < 16; off <<= 1) c += __shfl_xor(c, off);
    wk[k] = c;
  }
  float mw = fmaxf(wk[0], fmaxf(wk[1], wk[2]));
  float e0 = __expf(wk[0] - mw), e1 = __expf(wk[1] - mw), e2 = __expf(wk[2] - mw);
  float s = e0 + e1 + e2;
  float b0 = e0 / s, b1 = e1 / s, b2 = e2 / s;
  float emb = b0 * z0 + b1 * z1 + b2 * z2;
  out[OFF_EMB + (size_t)i * 64 + lane] = emb;
  if (lane == 0) {
    float* bp = out + OFF_BETA + (size_t)i * 3;
    bp[0] = b0; bp[1] = b1; bp[2] = b2;
  }
  zs[w][lane] = emb;
  int c8 = lane & 7;
  float lg = mlpb[c8];
  for (int d = 0; d < 64; ++d) lg = fmaf(zs[w][d], mlpw[d * 8 + c8], lg);
  float mx = lg;
#pragma unroll
  for (int off = 1; off < 8; off <<= 1) mx = fmaxf(mx, __shfl_xor(mx, off));
  float ex = __expf(lg - mx);
  float se = ex;
#pragma unroll
  for (int off = 1; off < 8; off <<= 1) se += __shfl_xor(se, off);
  float res = lg - mx - logf(se);
  if (lane < 8) out[OFF_OUTPUT + (size_t)i * 8 + lane] = res;
}

// ---------------------------------------------------------------------------
extern "C" void kernel_launch(void* const* d_in, const int* in_sizes, int n_in,
                              void* d_out, int out_size, void* d_ws, size_t ws_size,
                              hipStream_t stream) {
  const float* x   = (const float*)d_in[0];
  const int* sadj  = (const int*)d_in[1];
  const int* fadj  = (const int*)d_in[2];
  // nets: 0 = s1, 1 = s2, 2 = c
  const float* w1[3] = {(const float*)d_in[3], (const float*)d_in[7], (const float*)d_in[11]};
  const float* a1[3] = {(const float*)d_in[4], (const float*)d_in[8], (const float*)d_in[12]};
  const float* w2[3] = {(const float*)d_in[5], (const float*)d_in[9], (const float*)d_in[13]};
  const float* a2[3] = {(const float*)d_in[6], (const float*)d_in[10], (const float*)d_in[14]};
  const float* aw1  = (const float*)d_in[15];
  const float* ab1  = (const float*)d_in[16];
  const float* aw2  = (const float*)d_in[17];
  const float* mlpw = (const float*)d_in[18];
  const float* mlpb = (const float*)d_in[19];
  float* out = (float*)d_out;

  // workspace bump allocator (256B aligned)
  char* p = (char*)d_ws;
  auto alloc = [&](size_t bytes) { char* r = p; p += (bytes + 255) & ~(size_t)255; return r; };
  const size_t FRAG_ELEMS = (size_t)NWORDS * 8 * 64 * 8;   // ushort count (~770KB)
  u64* sbits = (u64*)alloc((size_t)NN * WPR * 8);
  u64* fbits = (u64*)alloc((size_t)NN * WPR * 8);
  float *Wh1[3], *f1[3], *g1[3];
  ushort *hi1[3], *lo1[3];
  for (int n = 0; n < 3; ++n) Wh1[n] = (float*)alloc((size_t)NN * 64 * 4);
  for (int n = 0; n < 3; ++n) f1[n] = (float*)alloc(6144 * 4);
  for (int n = 0; n < 3; ++n) g1[n] = (float*)alloc(6144 * 4);
  for (int n = 0; n < 3; ++n) { hi1[n] = (ushort*)alloc(FRAG_ELEMS * 2); lo1[n] = (ushort*)alloc(FRAG_ELEMS * 2); }
  float *h1[4], *Wh2[4], *f2[4], *g2[4];
  ushort *hi2[4], *lo2[4];
  for (int c = 0; c < 4; ++c) h1[c] = (float*)alloc((size_t)NN * 64 * 4);
  for (int c = 0; c < 4; ++c) Wh2[c] = (float*)alloc((size_t)NN * 64 * 4);
  for (int c = 0; c < 4; ++c) f2[c] = (float*)alloc(6144 * 4);
  for (int c = 0; c < 4; ++c) g2[c] = (float*)alloc(6144 * 4);
  for (int c = 0; c < 4; ++c) { hi2[c] = (ushort*)alloc(FRAG_ELEMS * 2); lo2[c] = (ushort*)alloc(FRAG_ELEMS * 2); }

  // combos: 0 emb1(s1,sadj) 1 com1(c,sadj) 2 com2(c,fadj) 3 emb2(s2,fadj)
  const int cn[4] = {0, 2, 2, 1};
  const u64* cb[4] = {sbits, sbits, fbits, fbits};
  float* cout[4] = {out + OFF_EMB1, out + OFF_COM1, out + OFF_COM2, out + OFF_EMB2};

  pack_kernel<<<dim3(3000), dim3(256), 0, stream>>>(sadj, fadj, sbits, fbits);

  GemmArgs4 ga1;
  for (int n = 0; n < 3; ++n) ga1.a[n] = {x, w1[n], a1[n], Wh1[n], f1[n], g1[n]};
  ga1.a[3] = ga1.a[0];
  gemm_fg_kernel<<<dim3(375, 3), dim3(256), 0, stream>>>(ga1, 512);

  TransArgs4 ta1;
  for (int n = 0; n < 3; ++n) ta1.a[n] = {Wh1[n], hi1[n], lo1[n]};
  ta1.a[3] = ta1.a[0];
  trans_kernel<<<dim3(NWORDS, 3), dim3(256), 0, stream>>>(ta1);

  Agg2Args4 aa1;
  for (int c = 0; c < 4; ++c) aa1.a[c] = {cb[c], f1[cn[c]], g1[cn[c]], hi1[cn[c]], lo1[cn[c]], h1[c]};
  agg2_kernel<0><<<dim3(376), dim3(512), 0, stream>>>(aa1);

  GemmArgs4 ga2;
  for (int c = 0; c < 4; ++c) ga2.a[c] = {h1[c], w2[cn[c]], a2[cn[c]], Wh2[c], f2[c], g2[c]};
  gemm_fg_kernel<<<dim3(375, 4), dim3(256), 0, stream>>>(ga2, 64);

  TransArgs4 ta2;
  for (int c = 0; c < 4; ++c) ta2.a[c] = {Wh2[c], hi2[c], lo2[c]};
  trans_kernel<<<dim3(NWORDS, 4), dim3(256), 0, stream>>>(ta2);

  Agg2Args4 aa2;
  for (int c = 0; c < 4; ++c) aa2.a[c] = {cb[c], f2[c], g2[c], hi2[c], lo2[c], cout[c]};
  agg2_kernel<1><<<dim3(376), dim3(512), 0, stream>>>(aa2);

  fuse_kernel<<<dim3(1500), dim3(256), 0, stream>>>(out, aw1, ab1, aw2, mlpw, mlpb);
}